// Round 6
// baseline (274.936 us; speedup 1.0000x reference)
//
#include <hip/hip_runtime.h>
#include <cstdint>

typedef unsigned long long ull;

#define N_BOX 8192
#define N_WORDS 128   // 8192 / 64
#define CH 512        // chunk size
#define WPC 8         // words per chunk
#define SUPW 80       // sup row stride in words (supports vb <= 5120; actual ~4096)

// ---------------- workspace layout ----------------
// sup    : 8192*80*8 = 5,242,880 @ 0         (row-major: sup[i][W] = word-W boxes suppressed by i)
// TD     : 16*4096*8 =   524,288 @ 5,242,880 (per-chunk transposed: TD[c][w][jl])
// boxes4 : 131072 @ 5,767,168
// scores : 32768  @ 5,898,240
// rank   : 32768  @ 5,931,008
// mask   : 1024   @ 5,963,776
// maxc   : 4      @ 5,964,800
// vb     : 4      @ 5,964,804
#define OFF_SUP    0
#define OFF_TD     5242880
#define OFF_BOXES  5767168
#define OFF_SCORES 5898240
#define OFF_RANK   5931008
#define OFF_MASK   5963776
#define OFF_MAXC   5964800
#define OFF_VB     5964804

__device__ __forceinline__ ull make_key(float s, int idx) {
    // positive floats: bit pattern is order-preserving. Reversed index in the
    // low 13 bits reproduces stable argsort(-conf): equal conf -> lower index first.
    return (((ull)__float_as_uint(s)) << 13) | (ull)(8191 - idx);
}

__device__ __forceinline__ float box_area(float4 b) {
    return __fmul_rn(__fsub_rn(b.z, b.x), __fsub_rn(b.w, b.y));
}

// exact replica of reference IoU rounding (_rn ops block FMA contraction); symmetric.
__device__ __forceinline__ bool iou_gt_half(float4 a, float aarea, float4 b, float barea) {
    float ix1 = fmaxf(a.x, b.x);
    float iy1 = fmaxf(a.y, b.y);
    float ix2 = fminf(a.z, b.z);
    float iy2 = fminf(a.w, b.w);
    float iw = fmaxf(__fsub_rn(ix2, ix1), 0.0f);
    float ih = fmaxf(__fsub_rn(iy2, iy1), 0.0f);
    float inter = __fmul_rn(iw, ih);
    float uni = __fsub_rn(__fadd_rn(aarea, barea), inter);
    float iou = __fdiv_rn(inter, fmaxf(uni, 1e-9f));
    return iou > 0.5f;
}

// K1: global conf max via int-bits atomicMax (conf>=0; poison 0xAA.. is negative int,
// so no pre-zero needed); zero rank + valid mask + vb.
__global__ __launch_bounds__(256) void k1_max_zero(const float* __restrict__ in,
                                                   int* __restrict__ maxci,
                                                   int* __restrict__ rank,
                                                   ull* __restrict__ mask,
                                                   int* __restrict__ vbp) {
    int t = threadIdx.x;
    int i = blockIdx.x * 256 + t;
    float c = in[i * 5 + 4];
    for (int off = 32; off; off >>= 1) c = fmaxf(c, __shfl_down(c, off));
    __shared__ float wm[4];
    if ((t & 63) == 0) wm[t >> 6] = c;
    __syncthreads();
    if (t == 0) {
        float m = fmaxf(fmaxf(wm[0], wm[1]), fmaxf(wm[2], wm[3]));
        atomicMax(maxci, __float_as_int(m));
    }
    rank[i] = 0;
    if (blockIdx.x == 0) {
        if (t < N_WORDS) mask[t] = 0ull;
        if (t == 0) *vbp = 0;
    }
}

// K2: rank via ballot-popcount. 4096 waves; wave (jg, ir): j-group jg (64 j in lanes),
// i-range ir (256 i). rank[i] += popc(ballot(kj > ki)). No LDS.
__global__ __launch_bounds__(1024) void k2_rank(const float* __restrict__ in,
                                                const float* __restrict__ maxc_p,
                                                int* __restrict__ rank) {
    int t = threadIdx.x;
    int lane = t & 63;
    int g = blockIdx.x * 16 + (t >> 6);     // 0..4095
    int jg = g & 127;
    int ibase = (g >> 7) * 256;
    float maxc = *maxc_p;
    int j = jg * 64 + lane;
    ull kj = make_key(__fdiv_rn(in[j * 5 + 4], maxc), j);
    #pragma unroll 1
    for (int blk = 0; blk < 4; ++blk) {
        int cnt = 0;
        #pragma unroll 8
        for (int ii = 0; ii < 64; ++ii) {
            int i = ibase + blk * 64 + ii;
            ull ki = make_key(__fdiv_rn(in[i * 5 + 4], maxc), i);
            int pc = __popcll(__ballot(kj > ki));
            cnt = (lane == ii) ? pc : cnt;
        }
        atomicAdd(&rank[ibase + blk * 64 + lane], cnt);   // coalesced 64-lane atomic
    }
}

// K3: scatter boxes/scores into sorted order, build valid bitmask + count
__global__ __launch_bounds__(256) void k3_scatter(const float* __restrict__ in,
                                                  const int* __restrict__ rank,
                                                  const float* __restrict__ maxc_p,
                                                  float4* __restrict__ boxes4,
                                                  float* __restrict__ scores,
                                                  ull* __restrict__ mask,
                                                  int* __restrict__ vbp) {
    int i = blockIdx.x * 256 + threadIdx.x;
    float cx = in[i * 5 + 0];
    float cy = in[i * 5 + 1];
    float w  = in[i * 5 + 2];
    float h  = in[i * 5 + 3];
    float c  = in[i * 5 + 4];
    float maxc = *maxc_p;
    float s = __fdiv_rn(c, maxc);
    int r = rank[i];
    float4 b;
    b.x = __fsub_rn(cx, __fmul_rn(w, 0.5f));
    b.y = __fsub_rn(cy, __fmul_rn(h, 0.5f));
    b.z = __fadd_rn(cx, __fmul_rn(w, 0.5f));
    b.w = __fadd_rn(cy, __fmul_rn(h, 0.5f));
    boxes4[r] = b;
    scores[r] = s;
    if (s >= 0.5f) {
        atomicOr(&mask[r >> 6], 1ull << (r & 63));
        atomicAdd(vbp, 1);
    }
}

// K4: build sup (row-major) + TD (per-chunk transposed diagonal).
//  bid < 4096: sup tile — 64 rows (i0=it*64) x 4 words (wt*4..+3). Gated:
//    lower-triangle skip, invalid-row skip, invalid-col skip, W>=SUPW skip.
//  bid >= 4096: TD tile — chunk c, 64 rows, all 8 words.
__global__ __launch_bounds__(256) void k4_build(const float4* __restrict__ boxes4,
                                                const float* __restrict__ scores,
                                                ull* __restrict__ sup,
                                                ull* __restrict__ TD) {
    int bid = blockIdx.x;
    int t = threadIdx.x;
    if (bid < 4096) {
        int it = bid >> 5;           // 0..127
        int wt = bid & 31;           // 0..31 (words wt*4..wt*4+3)
        int i0 = it * 64;
        if (wt * 4 >= SUPW) return;                  // beyond sup stride (never read)
        if ((wt + 1) * 256 <= i0) return;            // strictly lower triangle: never read
        if (scores[i0] < 0.5f) return;               // row tile invalid (desc scores)
        if (scores[wt * 256] < 0.5f) return;         // col tile never alive
        __shared__ float4 bi[64];
        __shared__ float4 bj[256];
        if (t < 64) bi[t] = boxes4[i0 + t];
        bj[t] = boxes4[wt * 256 + t];
        __syncthreads();
        int il = t >> 2;             // 0..63
        int wl = t & 3;              // 0..3
        int i = i0 + il;
        float4 a = bi[il];
        float aarea = box_area(a);
        ull word = 0ull;
        #pragma unroll 4
        for (int k = 0; k < 64; ++k) {
            float4 b = bj[wl * 64 + k];
            if (iou_gt_half(a, aarea, b, box_area(b))) word |= (1ull << k);
        }
        sup[(size_t)i * SUPW + wt * 4 + wl] = word;
    } else {
        int d = bid - 4096;          // 0..127
        int c = d >> 3;              // chunk 0..15
        int jt = d & 7;              // row tile (64 rows)
        if (scores[c * CH] < 0.5f) return;
        __shared__ float4 sb[CH];
        __shared__ float sa[CH];
        for (int i2 = t; i2 < CH; i2 += 256) {
            float4 b = boxes4[c * CH + i2];
            sb[i2] = b;
            sa[i2] = box_area(b);
        }
        __syncthreads();
        int r = t >> 2;              // 0..63
        int wl = t & 3;
        int jl = jt * 64 + r;
        float4 me = sb[jl];
        float ma = sa[jl];
        int wj = jl >> 6;
        #pragma unroll
        for (int p = 0; p < 2; ++p) {
            int w = wl + p * 4;
            int lim = (w < wj) ? 64 : ((w == wj) ? (jl & 63) : 0);
            ull bits = 0;
            for (int k = 0; k < lim; ++k)
                if (iou_gt_half(sb[w * 64 + k], sa[w * 64 + k], me, ma)) bits |= 1ull << k;
            TD[c * 4096 + w * 512 + jl] = bits;
        }
    }
}

// K5: chunk-sequential greedy NMS, one 1024-thread block.
// Wave 0: ballot-fixpoint scan of chunk c from LDS TD (proven R4 structure).
// Waves 1-15: prefetch next chunk's TD (double-buffered).
// Apply: per kept i, ONE coalesced 64-lane load of sup[i][W] covers all later
// words; sparse LDS atomicAnd. Kept list round-robined over 16 waves.
__global__ __launch_bounds__(1024) void k5_nms(const float4* __restrict__ boxes4,
                                               const float* __restrict__ scores,
                                               const ull* __restrict__ gmask,
                                               const ull* __restrict__ supg,
                                               const ull* __restrict__ TDg,
                                               const int* __restrict__ vbp,
                                               float* __restrict__ out) {
    __shared__ ull TDb[2][CH * WPC];            // 2 x 32 KB
    __shared__ unsigned amask32[2 * N_WORDS];
    __shared__ ull keptw[WPC];
    __shared__ int svb;
    int t = threadIdx.x;
    int lane = t & 63;
    int wave = t >> 6;

    if (t < 2 * N_WORDS) amask32[t] = ((const unsigned*)gmask)[t];
    if (t == 0) svb = *vbp;
    if (t < WPC) keptw[t] = 0;
    for (int i2 = t; i2 < CH * WPC; i2 += 1024) TDb[0][i2] = TDg[i2];   // chunk 0
    __syncthreads();

    int vb = svb;
    int nchv = (vb + CH - 1) / CH;
    int wv = (vb + 63) >> 6;
    int Wlim = (wv < SUPW) ? wv : SUPW;
    int cur = 0;
    for (int c = 0; c < nchv; ++c) {
        if (wave == 0) {
            const ull* T = TDb[cur];
            ull alive[WPC];
            #pragma unroll
            for (int w = 0; w < WPC; ++w)
                alive[w] = (ull)amask32[c * 16 + 2 * w] |
                           ((ull)amask32[c * 16 + 2 * w + 1] << 32);
            #pragma unroll
            for (int w = 0; w < WPC; ++w) {
                ull word = alive[w];
                if (!word) { if (lane == 0) keptw[w] = 0; continue; }
                ull td = T[w * 512 + w * 64 + lane];   // intra-word suppressors of my lane
                ull a2 = word, kept = 0;
                while (a2 & ~kept) {
                    bool al = (a2 >> lane) & 1;
                    bool kp = (kept >> lane) & 1;
                    ull nk = __ballot(al && !kp && ((td & a2) == 0));
                    ull nd = __ballot(al && !kp && ((td & kept) != 0));
                    kept |= nk;
                    a2 &= ~nd;
                }
                alive[w] = kept;
                #pragma unroll
                for (int j = 0; j < WPC; ++j) {
                    if (j <= w) continue;
                    if (!alive[j]) continue;
                    ull m = T[w * 512 + j * 64 + lane];
                    alive[j] &= ~__ballot((m & kept) != 0);
                }
                if (lane == 0) keptw[w] = kept;
            }
            if (lane == 0) {
                #pragma unroll
                for (int w = 0; w < WPC; ++w) {
                    amask32[c * 16 + 2 * w]     = (unsigned)alive[w];
                    amask32[c * 16 + 2 * w + 1] = (unsigned)(alive[w] >> 32);
                }
            }
        } else if (c + 1 < nchv) {
            int base = (c + 1) * CH * WPC;
            for (int i2 = t - 64; i2 < CH * WPC; i2 += 960)
                TDb[cur ^ 1][i2] = TDg[base + i2];
        }
        __syncthreads();

        // ---- apply kept_c to all later words via row-major sup ----
        int kidx = 0;
        for (int w8 = 0; w8 < WPC; ++w8) {
            ull kw = keptw[w8];
            while (kw) {
                int b = __builtin_ctzll(kw);
                kw &= kw - 1;
                if ((kidx & 15) == wave) {
                    int i = c * CH + w8 * 64 + b;
                    const ull* row = supg + (size_t)i * SUPW;
                    for (int Wb = WPC * (c + 1); Wb < Wlim; Wb += 64) {
                        int W = Wb + lane;
                        if (W < Wlim) {
                            ull s = row[W];
                            if (s) {
                                unsigned lo = (unsigned)s, hi = (unsigned)(s >> 32);
                                if (lo) atomicAnd(&amask32[2 * W], ~lo);
                                if (hi) atomicAnd(&amask32[2 * W + 1], ~hi);
                            }
                        }
                    }
                }
                ++kidx;
            }
        }
        cur ^= 1;
        __syncthreads();
    }

    // ---- epilogue: write all 8192 output rows ----
    #pragma unroll
    for (int rr = 0; rr < 8; ++rr) {
        int j = t * 8 + rr;
        bool kept = (amask32[j >> 5] >> (j & 31)) & 1u;
        float4 b = boxes4[j];
        float s = scores[j];
        out[j * 5 + 0] = kept ? b.x : 0.0f;
        out[j * 5 + 1] = kept ? b.y : 0.0f;
        out[j * 5 + 2] = kept ? b.z : 0.0f;
        out[j * 5 + 3] = kept ? b.w : 0.0f;
        out[j * 5 + 4] = kept ? s   : 0.0f;
    }
}

extern "C" void kernel_launch(void* const* d_in, const int* in_sizes, int n_in,
                              void* d_out, int out_size, void* d_ws, size_t ws_size,
                              hipStream_t stream) {
    const float* in = (const float*)d_in[0];
    char* ws = (char*)d_ws;
    ull* sup       = (ull*)(ws + OFF_SUP);
    ull* TD        = (ull*)(ws + OFF_TD);
    float4* boxes4 = (float4*)(ws + OFF_BOXES);
    float* scores  = (float*)(ws + OFF_SCORES);
    int* rank      = (int*)(ws + OFF_RANK);
    ull* mask      = (ull*)(ws + OFF_MASK);
    float* maxc    = (float*)(ws + OFF_MAXC);
    int* vbp       = (int*)(ws + OFF_VB);
    float* out     = (float*)d_out;

    k1_max_zero<<<32, 256, 0, stream>>>(in, (int*)maxc, rank, mask, vbp);
    k2_rank<<<256, 1024, 0, stream>>>(in, maxc, rank);
    k3_scatter<<<32, 256, 0, stream>>>(in, rank, maxc, boxes4, scores, mask, vbp);
    k4_build<<<4224, 256, 0, stream>>>(boxes4, scores, sup, TD);
    k5_nms<<<1, 1024, 0, stream>>>(boxes4, scores, mask, sup, TD, vbp, out);
}

// Round 7
// 166.615 us; speedup vs baseline: 1.6501x; 1.6501x over previous
//
#include <hip/hip_runtime.h>
#include <cstdint>

typedef unsigned long long ull;

#define N_BOX 8192
#define N_WORDS 128   // 8192 / 64
#define CH 512        // chunk size
#define WPC 8         // words per chunk

// ---------------- workspace layout ----------------
// TB (triangular transposed col-blocks): 61440 rows * 64 B = 3,932,160 @ 0
// TD (per-chunk transposed tables):      16 * 32 KB        =   524,288 @ 3,932,160
// boxes4 : 131072 @ 4,456,448
// scores : 32768  @ 4,587,520
#define OFF_TB     0
#define OFF_TD     3932160
#define OFF_BOXES  4456448
#define OFF_SCORES 4587520

// rows before chunk c in TB = sum_{c'<c} (8192 - 512*(c'+1))
__device__ __forceinline__ int rows_before(int c) {
    return 8192 * c - 256 * c * (c + 1);
}

__device__ __forceinline__ ull make_key(float s, int idx) {
    // positive floats: bit pattern is order-preserving. Reversed index in the
    // low 13 bits reproduces stable argsort(-conf): equal conf -> lower index first.
    return (((ull)__float_as_uint(s)) << 13) | (ull)(8191 - idx);
}

__device__ __forceinline__ float box_area(float4 b) {
    return __fmul_rn(__fsub_rn(b.z, b.x), __fsub_rn(b.w, b.y));
}

// exact replica of reference IoU rounding (_rn ops block FMA contraction); symmetric.
__device__ __forceinline__ bool iou_gt_half(float4 a, float aarea, float4 b, float barea) {
    float ix1 = fmaxf(a.x, b.x);
    float iy1 = fmaxf(a.y, b.y);
    float ix2 = fminf(a.z, b.z);
    float iy2 = fminf(a.w, b.w);
    float iw = fmaxf(__fsub_rn(ix2, ix1), 0.0f);
    float ih = fmaxf(__fsub_rn(iy2, iy1), 0.0f);
    float inter = __fmul_rn(iw, ih);
    float uni = __fsub_rn(__fadd_rn(aarea, barea), inter);
    float iou = __fdiv_rn(inter, fmaxf(uni, 1e-9f));
    return iou > 0.5f;
}

// KA: fused max + rank + scatter. 32 blocks x 1024 threads; block b owns
// i in [b*256, b*256+256). Each block redundantly computes the global max
// (identical reduction order -> bitwise identical), stages all 8192 keys in
// LDS, ranks its 256 i's (4-way j-split per i), scatters boxes/scores.
__global__ __launch_bounds__(1024) void ka_rank_scatter(const float* __restrict__ in,
                                                        float4* __restrict__ boxes4,
                                                        float* __restrict__ scores) {
    __shared__ ull skeys[N_BOX];         // 64 KB
    __shared__ float wm[16];
    __shared__ int rnk[256];
    int t = threadIdx.x;
    int bid = blockIdx.x;

    // ---- global max (redundant per block) ----
    float cf[8];
    float m = 0.0f;                      // conf >= 0
    #pragma unroll
    for (int k = 0; k < 8; ++k) {
        cf[k] = in[(k * 1024 + t) * 5 + 4];
        m = fmaxf(m, cf[k]);
    }
    for (int off = 32; off; off >>= 1) m = fmaxf(m, __shfl_down(m, off));
    if ((t & 63) == 0) wm[t >> 6] = m;
    if (t < 256) rnk[t] = 0;
    __syncthreads();
    float maxc = wm[0];
    #pragma unroll
    for (int k = 1; k < 16; ++k) maxc = fmaxf(maxc, wm[k]);

    // ---- keys in LDS ----
    #pragma unroll
    for (int k = 0; k < 8; ++k) {
        int j = k * 1024 + t;
        skeys[j] = make_key(__fdiv_rn(cf[k], maxc), j);
    }
    __syncthreads();

    // ---- rank my 256 i's; thread t handles i=(t&255), j-quarter q=(t>>8) ----
    {
        int il = t & 255;
        int i = bid * 256 + il;
        ull ki = skeys[i];
        int q = t >> 8;
        int cnt = 0;
        #pragma unroll 8
        for (int k = q * 2048; k < (q + 1) * 2048; ++k)
            cnt += (skeys[k] > ki) ? 1 : 0;
        atomicAdd(&rnk[il], cnt);
    }
    __syncthreads();

    // ---- scatter ----
    if (t < 256) {
        int i = bid * 256 + t;
        float cx = in[i * 5 + 0];
        float cy = in[i * 5 + 1];
        float w  = in[i * 5 + 2];
        float h  = in[i * 5 + 3];
        float s  = __fdiv_rn(in[i * 5 + 4], maxc);
        int r = rnk[t];
        float4 b;
        b.x = __fsub_rn(cx, __fmul_rn(w, 0.5f));
        b.y = __fsub_rn(cy, __fmul_rn(h, 0.5f));
        b.z = __fadd_rn(cx, __fmul_rn(w, 0.5f));
        b.w = __fadd_rn(cy, __fmul_rn(h, 0.5f));
        boxes4[r] = b;
        scores[r] = s;
    }
}

// KB: build suppression bit tables (R4-proven).
//  bid <  1920 : TB — 32 j-rows x 8 words for (chunk c, j-tile)
//  bid >= 1920 : TD — TD[c][w][jl] = mask of word-w chunk boxes suppressing jl
__global__ __launch_bounds__(256) void kb_build(const float4* __restrict__ boxes4,
                                                const float* __restrict__ scores,
                                                ull* __restrict__ TB,
                                                ull* __restrict__ TD) {
    __shared__ float4 sb[CH];
    __shared__ float sa[CH];
    int bid = blockIdx.x;
    int t = threadIdx.x;
    int c, j0;
    bool diag;
    if (bid >= 1920) {
        diag = true;
        int d = bid - 1920;
        c = d >> 4;
        j0 = (d & 15) * 32;                     // local jl tile
    } else {
        diag = false;
        c = 0;
        int rem = bid;
        while (rem >= 240 - 16 * c) { rem -= 240 - 16 * c; ++c; }
        j0 = CH * (c + 1) + rem * 32;           // global j tile
    }
    if (scores[c * CH] < 0.5f) return;          // chunk never a suppressor source
    if (!diag && scores[j0] < 0.5f) return;     // whole j-tile never alive

    for (int i = t; i < CH; i += 256) {
        float4 b = boxes4[c * CH + i];
        sb[i] = b;
        sa[i] = box_area(b);
    }
    __syncthreads();

    int w = t & 7;
    int jj = j0 + (t >> 3);
    if (diag) {
        int jl = jj;                            // 0..511
        float4 me = sb[jl];
        float ma = sa[jl];
        int wj = jl >> 6;
        int lim = (w < wj) ? 64 : ((w == wj) ? (jl & 63) : 0);
        ull bits = 0;
        for (int k = 0; k < lim; ++k)
            if (iou_gt_half(sb[w * 64 + k], sa[w * 64 + k], me, ma)) bits |= 1ull << k;
        TD[c * 4096 + w * 512 + jl] = bits;
    } else {
        int j = jj;
        float4 me = boxes4[j];
        float ma = box_area(me);
        ull bits = 0;
        for (int k = 0; k < 64; ++k)
            if (iou_gt_half(sb[w * 64 + k], sa[w * 64 + k], me, ma)) bits |= 1ull << k;
        TB[(size_t)(rows_before(c) + (j - CH * (c + 1))) * WPC + w] = bits;
    }
}

// KC: chunk-sequential greedy NMS, one 1024-thread block (R4-proven scan).
// vb computed internally from sorted-score prefix; alive mask init from prefix.
// Apply phase: UNCONDITIONAL TB row loads (branch-free -> pipelined vmcnt),
// gate only the LDS atomicAnd.
__global__ __launch_bounds__(1024) void kc_nms(const float4* __restrict__ boxes4,
                                               const float* __restrict__ scores,
                                               const ull* __restrict__ TBg,
                                               const ull* __restrict__ TDg,
                                               float* __restrict__ out) {
    __shared__ ull TDb[2][CH * WPC];            // 2 x 32 KB
    __shared__ unsigned amask32[2 * N_WORDS];
    __shared__ ull keptw[WPC];
    __shared__ int svb;
    int t = threadIdx.x;
    int lane = t & 63;
    int wave = t >> 6;

    // ---- vb from sorted-score prefix ----
    if (t == 0) svb = 0;
    __syncthreads();
    {
        int cnt = 0;
        #pragma unroll
        for (int k = 0; k < 8; ++k) cnt += (scores[k * 1024 + t] >= 0.5f) ? 1 : 0;
        ull bal = __ballot(cnt > 0);  // not enough; need full count:
        (void)bal;
        for (int off = 32; off; off >>= 1) cnt += __shfl_down(cnt, off);
        if (lane == 0) atomicAdd(&svb, cnt);
    }
    __syncthreads();
    int vb = svb;

    // ---- alive mask init from prefix; stage chunk-0 TD ----
    if (t < 2 * N_WORDS) {
        int base = (t >> 1) * 64 + (t & 1) * 32;
        int n = vb - base;
        amask32[t] = (n >= 32) ? 0xffffffffu : ((n <= 0) ? 0u : ((1u << n) - 1u));
    }
    if (t < WPC) keptw[t] = 0;
    for (int i2 = t; i2 < CH * WPC; i2 += 1024) TDb[0][i2] = TDg[i2];
    __syncthreads();

    int nchv = (vb + CH - 1) / CH;
    int cur = 0;
    for (int c = 0; c < nchv; ++c) {
        if (wave == 0) {
            const ull* T = TDb[cur];
            ull alive[WPC];
            #pragma unroll
            for (int w = 0; w < WPC; ++w)
                alive[w] = (ull)amask32[c * 16 + 2 * w] |
                           ((ull)amask32[c * 16 + 2 * w + 1] << 32);
            #pragma unroll
            for (int w = 0; w < WPC; ++w) {
                ull word = alive[w];
                if (!word) continue;
                ull td = T[w * 512 + w * 64 + lane];   // intra-word suppressors of my lane
                ull a2 = word, kept = 0;
                while (a2 & ~kept) {
                    bool al = (a2 >> lane) & 1;
                    bool kp = (kept >> lane) & 1;
                    ull nk = __ballot(al && !kp && ((td & a2) == 0));
                    ull nd = __ballot(al && !kp && ((td & kept) != 0));
                    kept |= nk;
                    a2 &= ~nd;
                }
                alive[w] = kept;
                #pragma unroll
                for (int j = 0; j < WPC; ++j) {
                    if (j <= w) continue;
                    if (!alive[j]) continue;
                    ull m = T[w * 512 + j * 64 + lane];
                    alive[j] &= ~__ballot((m & kept) != 0);
                }
            }
            if (lane == 0) {
                #pragma unroll
                for (int w = 0; w < WPC; ++w) {
                    amask32[c * 16 + 2 * w]     = (unsigned)alive[w];
                    amask32[c * 16 + 2 * w + 1] = (unsigned)(alive[w] >> 32);
                    keptw[w] = alive[w];
                }
            }
        } else if (c + 1 < nchv) {
            int base = (c + 1) * CH * WPC;
            for (int i2 = t - 64; i2 < CH * WPC; i2 += 960)
                TDb[cur ^ 1][i2] = TDg[base + i2];
        }
        __syncthreads();

        // ---- apply kept_c to all later alive j via TB (branch-free loads) ----
        ull kw[WPC];
        ull anyk = 0;
        #pragma unroll
        for (int k = 0; k < WPC; ++k) { kw[k] = keptw[k]; anyk |= kw[k]; }
        if (anyk) {
            const ull* TBc = TBg + (size_t)rows_before(c) * WPC;
            int jbase = CH * (c + 1);
            for (int j = jbase + t; j < vb; j += 1024) {
                const ull* r = TBc + (size_t)(j - jbase) * WPC;
                ull acc = 0;
                #pragma unroll
                for (int k = 0; k < WPC; ++k) acc |= r[k] & kw[k];
                if (acc) atomicAnd(&amask32[j >> 5], ~(1u << (j & 31)));
            }
        }
        cur ^= 1;
        __syncthreads();
    }

    // ---- epilogue: write all 8192 output rows ----
    #pragma unroll
    for (int rr = 0; rr < 8; ++rr) {
        int j = t * 8 + rr;
        bool kept = (amask32[j >> 5] >> (j & 31)) & 1u;
        float4 b = boxes4[j];
        float s = scores[j];
        out[j * 5 + 0] = kept ? b.x : 0.0f;
        out[j * 5 + 1] = kept ? b.y : 0.0f;
        out[j * 5 + 2] = kept ? b.z : 0.0f;
        out[j * 5 + 3] = kept ? b.w : 0.0f;
        out[j * 5 + 4] = kept ? s   : 0.0f;
    }
}

extern "C" void kernel_launch(void* const* d_in, const int* in_sizes, int n_in,
                              void* d_out, int out_size, void* d_ws, size_t ws_size,
                              hipStream_t stream) {
    const float* in = (const float*)d_in[0];
    char* ws = (char*)d_ws;
    ull* TB        = (ull*)(ws + OFF_TB);
    ull* TD        = (ull*)(ws + OFF_TD);
    float4* boxes4 = (float4*)(ws + OFF_BOXES);
    float* scores  = (float*)(ws + OFF_SCORES);
    float* out     = (float*)d_out;

    ka_rank_scatter<<<32, 1024, 0, stream>>>(in, boxes4, scores);
    kb_build<<<2176, 256, 0, stream>>>(boxes4, scores, TB, TD);
    kc_nms<<<1, 1024, 0, stream>>>(boxes4, scores, TB, TD, out);
}

// Round 8
// 137.181 us; speedup vs baseline: 2.0042x; 1.2146x over previous
//
#include <hip/hip_runtime.h>
#include <cstdint>

typedef unsigned long long ull;

#define N_BOX 8192
#define N_WORDS 128   // 8192 / 64
#define CH 512        // chunk size
#define WPC 8         // words per chunk

// ---------------- workspace layout ----------------
// TB (triangular transposed col-blocks): 61440 rows * 64 B = 3,932,160 @ 0
// TD (per-chunk transposed tables):      16 * 32 KB        =   524,288 @ 3,932,160
// boxes4 : 131072 @ 4,456,448
// scores : 32768  @ 4,587,520
// rank   : 32768  @ 4,620,288
// maxc   : 4      @ 4,653,056
#define OFF_TB     0
#define OFF_TD     3932160
#define OFF_BOXES  4456448
#define OFF_SCORES 4587520
#define OFF_RANK   4620288
#define OFF_MAXC   4653056

// rows before chunk c in TB = sum_{c'<c} (8192 - 512*(c'+1))
__device__ __forceinline__ int rows_before(int c) {
    return 8192 * c - 256 * c * (c + 1);
}

__device__ __forceinline__ ull make_key(float s, int idx) {
    // positive floats: bit pattern is order-preserving. Reversed index in the
    // low 13 bits reproduces stable argsort(-conf): equal conf -> lower index first.
    return (((ull)__float_as_uint(s)) << 13) | (ull)(8191 - idx);
}

__device__ __forceinline__ float box_area(float4 b) {
    return __fmul_rn(__fsub_rn(b.z, b.x), __fsub_rn(b.w, b.y));
}

// exact replica of reference IoU rounding (_rn ops block FMA contraction); symmetric.
__device__ __forceinline__ bool iou_gt_half(float4 a, float aarea, float4 b, float barea) {
    float ix1 = fmaxf(a.x, b.x);
    float iy1 = fmaxf(a.y, b.y);
    float ix2 = fminf(a.z, b.z);
    float iy2 = fminf(a.w, b.w);
    float iw = fmaxf(__fsub_rn(ix2, ix1), 0.0f);
    float ih = fmaxf(__fsub_rn(iy2, iy1), 0.0f);
    float inter = __fmul_rn(iw, ih);
    float uni = __fsub_rn(__fadd_rn(aarea, barea), inter);
    float iou = __fdiv_rn(inter, fmaxf(uni, 1e-9f));
    return iou > 0.5f;
}

// K1: max-reduce conf (single block), zero rank
__global__ __launch_bounds__(1024) void k1_max_zero(const float* __restrict__ in,
                                                    float* __restrict__ maxc,
                                                    int* __restrict__ rank) {
    int t = threadIdx.x;
    float m = 0.0f;  // conf is uniform [0,1): non-negative
    for (int k = t; k < N_BOX; k += 1024) m = fmaxf(m, in[k * 5 + 4]);
    for (int off = 32; off; off >>= 1) m = fmaxf(m, __shfl_down(m, off));
    __shared__ float wm[16];
    if ((t & 63) == 0) wm[t >> 6] = m;
    __syncthreads();
    if (t == 0) {
        float mm = wm[0];
        for (int k = 1; k < 16; ++k) mm = fmaxf(mm, wm[k]);
        *maxc = mm;
    }
    for (int k = t; k < N_BOX; k += 1024) rank[k] = 0;
}

// K2: rank[i] = #{ j : key_j > key_i }  (descending sort position, stable ties)
__global__ __launch_bounds__(256) void k2_rank(const float* __restrict__ in,
                                               const float* __restrict__ maxc_p,
                                               int* __restrict__ rank) {
    __shared__ ull keys[1024];
    int t = threadIdx.x;
    int bx = blockIdx.x;
    int it = bx & 31;       // i tile: 256 boxes
    int jt = bx >> 5;       // j tile: 1024 boxes (8 tiles)
    float maxc = *maxc_p;
    for (int r = 0; r < 4; ++r) {
        int j = jt * 1024 + r * 256 + t;
        float s = __fdiv_rn(in[j * 5 + 4], maxc);
        keys[r * 256 + t] = make_key(s, j);
    }
    __syncthreads();
    int i = it * 256 + t;
    ull ki = make_key(__fdiv_rn(in[i * 5 + 4], maxc), i);
    int cnt = 0;
    #pragma unroll 8
    for (int k = 0; k < 1024; ++k) cnt += (keys[k] > ki) ? 1 : 0;
    atomicAdd(&rank[i], cnt);
}

// K3: scatter boxes/scores into sorted order
__global__ __launch_bounds__(256) void k3_scatter(const float* __restrict__ in,
                                                  const int* __restrict__ rank,
                                                  const float* __restrict__ maxc_p,
                                                  float4* __restrict__ boxes4,
                                                  float* __restrict__ scores) {
    int i = blockIdx.x * 256 + threadIdx.x;
    float cx = in[i * 5 + 0];
    float cy = in[i * 5 + 1];
    float w  = in[i * 5 + 2];
    float h  = in[i * 5 + 3];
    float c  = in[i * 5 + 4];
    float maxc = *maxc_p;
    float s = __fdiv_rn(c, maxc);
    int r = rank[i];
    float4 b;
    b.x = __fsub_rn(cx, __fmul_rn(w, 0.5f));
    b.y = __fsub_rn(cy, __fmul_rn(h, 0.5f));
    b.z = __fadd_rn(cx, __fmul_rn(w, 0.5f));
    b.w = __fadd_rn(cy, __fmul_rn(h, 0.5f));
    boxes4[r] = b;
    scores[r] = s;
}

// K4: build suppression bit tables (R4-proven).
//  bid <  1920 : TB — 32 j-rows x 8 words for (chunk c, j-tile)
//  bid >= 1920 : TD — TD[c][w][jl] = mask of word-w chunk boxes suppressing jl
__global__ __launch_bounds__(256) void k4_build(const float4* __restrict__ boxes4,
                                                const float* __restrict__ scores,
                                                ull* __restrict__ TB,
                                                ull* __restrict__ TD) {
    __shared__ float4 sb[CH];
    __shared__ float sa[CH];
    int bid = blockIdx.x;
    int t = threadIdx.x;
    int c, j0;
    bool diag;
    if (bid >= 1920) {
        diag = true;
        int d = bid - 1920;
        c = d >> 4;
        j0 = (d & 15) * 32;                     // local jl tile
    } else {
        diag = false;
        c = 0;
        int rem = bid;
        while (rem >= 240 - 16 * c) { rem -= 240 - 16 * c; ++c; }
        j0 = CH * (c + 1) + rem * 32;           // global j tile
    }
    if (scores[c * CH] < 0.5f) return;          // chunk never a suppressor source
    if (!diag && scores[j0] < 0.5f) return;     // whole j-tile never alive

    for (int i = t; i < CH; i += 256) {
        float4 b = boxes4[c * CH + i];
        sb[i] = b;
        sa[i] = box_area(b);
    }
    __syncthreads();

    int w = t & 7;
    int jj = j0 + (t >> 3);
    if (diag) {
        int jl = jj;                            // 0..511
        float4 me = sb[jl];
        float ma = sa[jl];
        int wj = jl >> 6;
        int lim = (w < wj) ? 64 : ((w == wj) ? (jl & 63) : 0);
        ull bits = 0;
        for (int k = 0; k < lim; ++k)
            if (iou_gt_half(sb[w * 64 + k], sa[w * 64 + k], me, ma)) bits |= 1ull << k;
        TD[c * 4096 + w * 512 + jl] = bits;
    } else {
        int j = jj;
        float4 me = boxes4[j];
        float ma = box_area(me);
        ull bits = 0;
        for (int k = 0; k < 64; ++k)
            if (iou_gt_half(sb[w * 64 + k], sa[w * 64 + k], me, ma)) bits |= 1ull << k;
        TB[(size_t)(rows_before(c) + (j - CH * (c + 1))) * WPC + w] = bits;
    }
}

// K5: chunk-sequential greedy NMS, one 1024-thread block.
//  Wave 0       : scan chunk c (TD-col preload -> ballot fixpoint -> VALU applies).
//  Waves 1-7    : DEFERRED apply of kept[c-1] to chunks >= c+1 (overlapped w/ scan).
//  Waves 8-15   : prefetch next chunk's TD (double-buffered).
//  After barrier: all waves sync-apply kept[c] to chunk c+1 only.
__global__ __launch_bounds__(1024) void k5_nms(const float4* __restrict__ boxes4,
                                               const float* __restrict__ scores,
                                               const ull* __restrict__ TBg,
                                               const ull* __restrict__ TDg,
                                               float* __restrict__ out) {
    __shared__ ull TDb[2][CH * WPC];            // 2 x 32 KB
    __shared__ unsigned amask32[2 * N_WORDS];
    __shared__ ull keptA[WPC];                  // kept of current chunk (scan output)
    __shared__ ull keptB[WPC];                  // kept of previous chunk (deferred apply)
    __shared__ int svb;
    int t = threadIdx.x;
    int lane = t & 63;
    int wave = t >> 6;

    // ---- vb from sorted-score prefix ----
    if (t == 0) svb = 0;
    __syncthreads();
    {
        int cnt = 0;
        #pragma unroll
        for (int k = 0; k < 8; ++k) cnt += (scores[k * 1024 + t] >= 0.5f) ? 1 : 0;
        for (int off = 32; off; off >>= 1) cnt += __shfl_down(cnt, off);
        if (lane == 0) atomicAdd(&svb, cnt);
    }
    __syncthreads();
    int vb = svb;

    // ---- alive mask from prefix; zero kept; stage chunk-0 TD ----
    if (t < 2 * N_WORDS) {
        int n = vb - t * 32;
        amask32[t] = (n >= 32) ? 0xffffffffu : ((n <= 0) ? 0u : ((1u << n) - 1u));
    }
    if (t < WPC) { keptA[t] = 0; keptB[t] = 0; }
    for (int i2 = t; i2 < CH * WPC; i2 += 1024) TDb[0][i2] = TDg[i2];
    __syncthreads();

    int nchv = (vb + CH - 1) / CH;
    int cur = 0;
    for (int c = 0; c < nchv; ++c) {
        if (wave == 0) {
            // ================= scan chunk c =================
            const ull* T = TDb[cur];
            ull alive[WPC];
            #pragma unroll
            for (int w = 0; w < WPC; ++w)
                alive[w] = (ull)amask32[c * 16 + 2 * w] |
                           ((ull)amask32[c * 16 + 2 * w + 1] << 32);
            #pragma unroll
            for (int w = 0; w < WPC; ++w) {
                ull word = alive[w];
                if (!word) continue;
                // preload ALL TD columns for this word (j >= w) -> independent,
                // pipelined ds_reads; fixpoint+applies below are memory-free.
                ull Tc[WPC];
                #pragma unroll
                for (int j = 0; j < WPC; ++j)
                    if (j >= w) Tc[j] = T[w * 512 + j * 64 + lane];
                ull td = Tc[w];                  // intra-word suppressors of my lane
                ull a2 = word, kept = 0;
                while (a2 & ~kept) {
                    bool al = (a2 >> lane) & 1;
                    bool kp = (kept >> lane) & 1;
                    ull nk = __ballot(al && !kp && ((td & a2) == 0));
                    ull nd = __ballot(al && !kp && ((td & kept) != 0));
                    kept |= nk;
                    a2 &= ~nd;
                }
                alive[w] = kept;
                #pragma unroll
                for (int j = 0; j < WPC; ++j) {
                    if (j <= w) continue;
                    if (!alive[j]) continue;
                    alive[j] &= ~__ballot((Tc[j] & kept) != 0);
                }
            }
            if (lane == 0) {
                #pragma unroll
                for (int w = 0; w < WPC; ++w) {
                    amask32[c * 16 + 2 * w]     = (unsigned)alive[w];
                    amask32[c * 16 + 2 * w + 1] = (unsigned)(alive[w] >> 32);
                    keptA[w] = alive[w];
                }
            }
        } else if (wave < 8) {
            // ===== deferred apply: kept[c-1] -> j in chunks >= c+1 =====
            if (c > 0) {
                ull kw[WPC];
                ull anyk = 0;
                #pragma unroll
                for (int k = 0; k < WPC; ++k) { kw[k] = keptB[k]; anyk |= kw[k]; }
                if (anyk) {
                    const ull* TBc = TBg + (size_t)rows_before(c - 1) * WPC;
                    int jbase = CH * c;              // TB rows of chunk c-1 start at j = CH*c
                    int jstart = CH * (c + 1);       // chunk c handled synchronously last iter
                    for (int j = jstart + (t - 64); j < vb; j += 448) {
                        if ((amask32[j >> 5] >> (j & 31)) & 1u) {
                            const ull* r = TBc + (size_t)(j - jbase) * WPC;
                            ull acc = 0;
                            #pragma unroll
                            for (int k = 0; k < WPC; ++k) acc |= r[k] & kw[k];
                            if (acc) atomicAnd(&amask32[j >> 5], ~(1u << (j & 31)));
                        }
                    }
                }
            }
        } else {
            // ===== prefetch next chunk's TD =====
            if (c + 1 < nchv) {
                int base = (c + 1) * CH * WPC;
                for (int i2 = t - 512; i2 < CH * WPC; i2 += 512)
                    TDb[cur ^ 1][i2] = TDg[base + i2];
            }
        }
        __syncthreads();

        // ===== sync apply: kept[c] -> chunk c+1 only =====
        if (c + 1 < nchv) {
            ull kw[WPC];
            ull anyk = 0;
            #pragma unroll
            for (int k = 0; k < WPC; ++k) { kw[k] = keptA[k]; anyk |= kw[k]; }
            if (anyk) {
                const ull* TBc = TBg + (size_t)rows_before(c) * WPC;
                int jbase = CH * (c + 1);
                int jend = jbase + CH;
                if (jend > vb) jend = vb;
                for (int j = jbase + t; j < jend; j += 1024) {
                    if ((amask32[j >> 5] >> (j & 31)) & 1u) {
                        const ull* r = TBc + (size_t)(j - jbase) * WPC;
                        ull acc = 0;
                        #pragma unroll
                        for (int k = 0; k < WPC; ++k) acc |= r[k] & kw[k];
                        if (acc) atomicAnd(&amask32[j >> 5], ~(1u << (j & 31)));
                    }
                }
            }
        }
        if (t < WPC) keptB[t] = keptA[t];
        cur ^= 1;
        __syncthreads();
    }

    // ---- epilogue: write all 8192 output rows ----
    #pragma unroll
    for (int rr = 0; rr < 8; ++rr) {
        int j = t * 8 + rr;
        bool kept = (amask32[j >> 5] >> (j & 31)) & 1u;
        float4 b = boxes4[j];
        float s = scores[j];
        out[j * 5 + 0] = kept ? b.x : 0.0f;
        out[j * 5 + 1] = kept ? b.y : 0.0f;
        out[j * 5 + 2] = kept ? b.z : 0.0f;
        out[j * 5 + 3] = kept ? b.w : 0.0f;
        out[j * 5 + 4] = kept ? s   : 0.0f;
    }
}

extern "C" void kernel_launch(void* const* d_in, const int* in_sizes, int n_in,
                              void* d_out, int out_size, void* d_ws, size_t ws_size,
                              hipStream_t stream) {
    const float* in = (const float*)d_in[0];
    char* ws = (char*)d_ws;
    ull* TB        = (ull*)(ws + OFF_TB);
    ull* TD        = (ull*)(ws + OFF_TD);
    float4* boxes4 = (float4*)(ws + OFF_BOXES);
    float* scores  = (float*)(ws + OFF_SCORES);
    int* rank      = (int*)(ws + OFF_RANK);
    float* maxc    = (float*)(ws + OFF_MAXC);
    float* out     = (float*)d_out;

    k1_max_zero<<<1, 1024, 0, stream>>>(in, maxc, rank);
    k2_rank<<<256, 256, 0, stream>>>(in, maxc, rank);
    k3_scatter<<<32, 256, 0, stream>>>(in, rank, maxc, boxes4, scores);
    k4_build<<<2176, 256, 0, stream>>>(boxes4, scores, TB, TD);
    k5_nms<<<1, 1024, 0, stream>>>(boxes4, scores, TB, TD, out);
}